// Round 4
// baseline (394.923 us; speedup 1.0000x reference)
//
#include <hip/hip_runtime.h>

#define BB 128
#define II 512
#define HH 256
#define OO 32
#define FF 16
#define OF 512
#define CI 32          // i-rows per sub-chunk
#define NP 8           // partials per b (II / 64)
#define XPAD 260       // padded LDS row stride (floats) for x tiles
#define CSTR 36        // padded LDS row stride for c tile

// ---------------- Kernel A: partial column-sums of x over i ----------------
__global__ __launch_bounds__(256) void k_xsum(
    const float* __restrict__ x, float* __restrict__ xsum_part) {
  int t = threadIdx.x;                 // h
  int blk = blockIdx.x;                // b*8 + chunk
  int b = blk >> 3, ch = blk & 7;
  const float* xp = x + ((size_t)b * II + (size_t)ch * 64) * HH + t;
  float a = 0.f;
#pragma unroll 8
  for (int i = 0; i < 64; ++i) a += xp[(size_t)i * HH];
  xsum_part[(size_t)blk * HH + t] = a;
}

// ---------------- Kernel B: v1 = squash((1/32) * xsum @ W) ----------------
__global__ __launch_bounds__(512) void k_v1(
    const float* __restrict__ xsum_part, const float* __restrict__ W,
    float* __restrict__ v) {
  __shared__ float xs[HH];
  int t = threadIdx.x;
  int b = blockIdx.x;
  if (t < HH) {
    float a = 0.f;
#pragma unroll
    for (int ch = 0; ch < 8; ++ch) a += xsum_part[((size_t)b * 8 + ch) * HH + t];
    xs[t] = a;
  }
  __syncthreads();
  float acc = 0.f;
#pragma unroll 4
  for (int h = 0; h < HH; ++h)
    acc += xs[h] * W[(size_t)h * OF + t];
  acc *= (1.0f / 32.0f);
  float n2 = acc * acc;
#pragma unroll
  for (int mask = 1; mask < 16; mask <<= 1) n2 += __shfl_xor(n2, mask);
  float scale = sqrtf(n2) / (1.f + n2);
  v[(size_t)b * OF + t] = acc * scale;
}

// ---------------- Kernel C: wvT[b,o,h] = sum_f W[h,o*16+f] * v[b,o,f] ------
// grid = 128 blocks: blk = hq*32 + o. W is read exactly once device-wide.
__global__ __launch_bounds__(256) void k_wv(
    const float* __restrict__ W, const float* __restrict__ v,
    float* __restrict__ wvT) {
  __shared__ float Ws[64 * 17];        // W[h_local][f], padded
  __shared__ float vsb[BB * 17];       // v[b][f] for this o, padded
  int t = threadIdx.x;
  int blk = blockIdx.x;
  int o = blk & 31, hq = blk >> 5;     // hq in [0,4)
  // stage W slice: 64 h x 16 f
#pragma unroll
  for (int jj = 0; jj < 4; ++jj) {
    int idx = jj * 256 + t;            // 0..1023
    int hl = idx >> 4, f = idx & 15;
    Ws[hl * 17 + f] = W[((size_t)(hq * 64 + hl)) * OF + o * FF + f];
  }
  // stage v[b][o][:] for all b
#pragma unroll
  for (int jj = 0; jj < 8; ++jj) {
    int idx = jj * 256 + t;            // 0..2047
    int b = idx >> 4, f = idx & 15;
    vsb[b * 17 + f] = v[((size_t)b * OO + o) * FF + f];
  }
  __syncthreads();
  int hl = t & 63, bq = t >> 6;        // wave-uniform bq
  for (int bb = 0; bb < BB; bb += 4) {
    int b = bb + bq;
    float acc = 0.f;
#pragma unroll
    for (int f = 0; f < FF; ++f) acc += Ws[hl * 17 + f] * vsb[b * 17 + f];
    wvT[((size_t)b * OO + o) * HH + hq * 64 + hl] = acc;   // coalesced
  }
}

// ---------------- Kernel D (fused): blog -> softmax -> partial cx ----------
// grid = B*NP (1024), block = 256, 4 blocks/CU (LDS 37 KB). Two CI=32
// sub-chunks per block; phase-3 accumulators carried in registers.
__global__ __launch_bounds__(256, 4) void k_route(
    const float* __restrict__ x, const float* __restrict__ wvT,
    float* __restrict__ cxp) {
  __shared__ float xls[CI * XPAD];     // 33.3 KB
  __shared__ float cs[CI * CSTR];      // 4.6 KB
  int t = threadIdx.x;
  int blk = blockIdx.x;
  int b = blk >> 3, p = blk & 7;

  // phase-3 tile: 8 o x 4 h per thread
  int hg = t & 63, og3 = t >> 6;
  int h0 = hg * 4, o0 = og3 * 8;
  float4 a4[8];
#pragma unroll
  for (int j = 0; j < 8; ++j) a4[j] = make_float4(0.f, 0.f, 0.f, 0.f);

  // phase-2 tile: rows {ig, ig+16} x o {2og, 2og+1}
  int og = t & 15, ig = t >> 4;
  const float* wp0 = wvT + ((size_t)b * OO + 2 * og) * HH;
  const float* wp1 = wp0 + HH;

  for (int sub = 0; sub < 2; ++sub) {
    if (sub) __syncthreads();          // xls reused
    // ---- stage 32 rows of x ----
    const float4* xp4 = (const float4*)(x + ((size_t)b * II + p * 64 + sub * 32) * HH);
#pragma unroll
    for (int jj = 0; jj < 8; ++jj) {
      int idx = jj * 256 + t;          // 2048 float4
      int row = idx >> 6, col = idx & 63;
      *(float4*)&xls[row * XPAD + col * 4] = xp4[idx];
    }
    __syncthreads();
    // ---- phase 2: logits + softmax ----
    {
      float acc00 = 0.f, acc01 = 0.f, acc10 = 0.f, acc11 = 0.f;
#pragma unroll 8
      for (int h = 0; h < HH; h += 4) {
        float4 x0 = *(const float4*)&xls[ig * XPAD + h];
        float4 x1 = *(const float4*)&xls[(ig + 16) * XPAD + h];
        float4 w0 = *(const float4*)&wp0[h];
        float4 w1 = *(const float4*)&wp1[h];
        acc00 += x0.x * w0.x + x0.y * w0.y + x0.z * w0.z + x0.w * w0.w;
        acc01 += x0.x * w1.x + x0.y * w1.y + x0.z * w1.z + x0.w * w1.w;
        acc10 += x1.x * w0.x + x1.y * w0.y + x1.z * w0.z + x1.w * w0.w;
        acc11 += x1.x * w1.x + x1.y * w1.y + x1.z * w1.z + x1.w * w1.w;
      }
      // softmax over o (reduce across the 16 og lanes; masks<16 keep ig fixed)
      float m0 = fmaxf(acc00, acc01);
      float m1 = fmaxf(acc10, acc11);
#pragma unroll
      for (int mask = 1; mask < 16; mask <<= 1) {
        m0 = fmaxf(m0, __shfl_xor(m0, mask));
        m1 = fmaxf(m1, __shfl_xor(m1, mask));
      }
      float e00 = __expf(acc00 - m0), e01 = __expf(acc01 - m0);
      float e10 = __expf(acc10 - m1), e11 = __expf(acc11 - m1);
      float s0 = e00 + e01, s1 = e10 + e11;
#pragma unroll
      for (int mask = 1; mask < 16; mask <<= 1) {
        s0 += __shfl_xor(s0, mask);
        s1 += __shfl_xor(s1, mask);
      }
      float inv0 = 1.f / s0, inv1 = 1.f / s1;
      *(float2*)&cs[ig * CSTR + 2 * og] = make_float2(e00 * inv0, e01 * inv0);
      *(float2*)&cs[(ig + 16) * CSTR + 2 * og] = make_float2(e10 * inv1, e11 * inv1);
    }
    __syncthreads();
    // ---- phase 3: accumulate partial cx over this sub-chunk ----
#pragma unroll 4
    for (int i = 0; i < CI; ++i) {
      float4 x4 = *(const float4*)&xls[i * XPAD + h0];
      float4 c0 = *(const float4*)&cs[i * CSTR + o0];
      float4 c1 = *(const float4*)&cs[i * CSTR + o0 + 4];
      float cv[8] = {c0.x, c0.y, c0.z, c0.w, c1.x, c1.y, c1.z, c1.w};
#pragma unroll
      for (int j = 0; j < 8; ++j) {
        a4[j].x += cv[j] * x4.x;
        a4[j].y += cv[j] * x4.y;
        a4[j].z += cv[j] * x4.z;
        a4[j].w += cv[j] * x4.w;
      }
    }
  }
  // write partial [blk][o0+j][h0..h0+3]
  float* outp = cxp + ((size_t)blk * OO + o0) * HH + h0;
#pragma unroll
  for (int j = 0; j < 8; ++j)
    *(float4*)&outp[(size_t)j * HH] = a4[j];
}

// ---------------- Kernel E: reduce partials + v = squash(cx @ W) -----------
// grid = B*O (4096), block = 256
__global__ __launch_bounds__(256) void k_v2(
    const float* __restrict__ cxp, const float* __restrict__ W,
    float* __restrict__ v, float* __restrict__ out, int final_) {
  __shared__ float cxs[HH];
  __shared__ float red[4][16];
  int t = threadIdx.x;
  int blk = blockIdx.x;                // b*32 + o
  int b = blk >> 5, o = blk & 31;
  // phase A: 8-way partial sum, coalesced (t = h)
  {
    const float* cp = cxp + (((size_t)b * NP) * OO + o) * HH + t;
    float a = 0.f;
#pragma unroll
    for (int p = 0; p < NP; ++p) a += cp[(size_t)p * OO * HH];
    cxs[t] = a;
  }
  __syncthreads();
  // phase B: acc[f] = sum_h cxs[h] * W[h][o*16+f]
  int f = t & 15, hq = t >> 4;
  const float* wp = W + (size_t)hq * 16 * OF + o * FF + f;
  float acc = 0.f;
#pragma unroll
  for (int j = 0; j < 16; ++j)
    acc += cxs[hq * 16 + j] * wp[(size_t)j * OF];
  acc += __shfl_xor(acc, 16);
  acc += __shfl_xor(acc, 32);          // now sum over 4 hq within wave
  if ((t & 63) < 16) red[t >> 6][f] = acc;
  __syncthreads();
  if (t < 16) {
    float a = red[0][t] + red[1][t] + red[2][t] + red[3][t];
    float n2 = a * a;
#pragma unroll
    for (int mask = 1; mask < 16; mask <<= 1) n2 += __shfl_xor(n2, mask);
    float scale = sqrtf(n2) / (1.f + n2);
    float res = a * scale;
    if (final_) out[(size_t)blk * FF + t] = res;
    else v[(size_t)blk * FF + t] = res;
  }
}

extern "C" void kernel_launch(void* const* d_in, const int* in_sizes, int n_in,
                              void* d_out, int out_size, void* d_ws, size_t ws_size,
                              hipStream_t stream) {
  const float* x = (const float*)d_in[0];  // [128,512,256] fp32
  const float* W = (const float*)d_in[1];  // [1,256,512]   fp32
  float* out = (float*)d_out;              // [128,32,16]   fp32
  float* ws = (float*)d_ws;
  float* xsum_part = ws;                  // B*8*H = 262144
  float* v   = ws + 262144;               // B*O*F = 65536
  float* wvT = ws + 327680;               // B*O*H = 1048576
  float* cxp = ws + 1376256;              // B*NP*O*H = 8388608

  k_xsum<<<BB * 8, 256, 0, stream>>>(x, xsum_part);
  k_v1<<<BB, 512, 0, stream>>>(xsum_part, W, v);
  for (int it = 0; it < 2; ++it) {
    k_wv<<<128, 256, 0, stream>>>(W, v, wvT);
    k_route<<<BB * NP, 256, 0, stream>>>(x, wvT, cxp);
    k_v2<<<BB * OO, 256, 0, stream>>>(cxp, W, v, out, it == 1);
  }
}

// Round 5
// 189.809 us; speedup vs baseline: 2.0806x; 2.0806x over previous
//
#include <hip/hip_runtime.h>

#define BB 128
#define II 512
#define HH 256
#define OO 32
#define FF 16
#define OF 512
#define CI 64          // i-rows per route block
#define NP 8           // partials per b (II / CI)
#define X16STR 264     // ushort stride of x bf16 LDS row (528 B, 16B-aligned)
#define CSTRI 68       // fp32 stride of logits LDS [o][i]
#define C2STR 36       // fp32 stride of softmaxed c LDS [i][o] (144 B, 16B-aligned)

typedef __attribute__((ext_vector_type(8))) short short8;   // 8 bf16 (4 VGPRs)
typedef __attribute__((ext_vector_type(4))) float floatx4;  // MFMA C/D

__device__ __forceinline__ ushort f2bf(float f) {           // RTN-even
  unsigned u = __float_as_uint(f);
  u += 0x7FFFu + ((u >> 16) & 1u);
  return (ushort)(u >> 16);
}
__device__ __forceinline__ float bf2f(ushort u) {
  return __uint_as_float(((unsigned)u) << 16);
}

// ---------------- Kernel A: partial column-sums of x over i ----------------
__global__ __launch_bounds__(256) void k_xsum(
    const float* __restrict__ x, float* __restrict__ xsum_part) {
  int t = threadIdx.x;                 // h
  int blk = blockIdx.x;                // b*8 + chunk
  int b = blk >> 3, ch = blk & 7;
  const float* xp = x + ((size_t)b * II + (size_t)ch * 64) * HH + t;
  float a = 0.f;
#pragma unroll 8
  for (int i = 0; i < 64; ++i) a += xp[(size_t)i * HH];
  xsum_part[(size_t)blk * HH + t] = a;
}

// ---------------- Kernel B: v1 = squash((1/32) * xsum @ W) ----------------
__global__ __launch_bounds__(512) void k_v1(
    const float* __restrict__ xsum_part, const float* __restrict__ W,
    float* __restrict__ v) {
  __shared__ float xs[HH];
  int t = threadIdx.x;
  int b = blockIdx.x;
  if (t < HH) {
    float a = 0.f;
#pragma unroll
    for (int ch = 0; ch < 8; ++ch) a += xsum_part[((size_t)b * 8 + ch) * HH + t];
    xs[t] = a;
  }
  __syncthreads();
  float acc = 0.f;
#pragma unroll 4
  for (int h = 0; h < HH; ++h)
    acc += xs[h] * W[(size_t)h * OF + t];
  acc *= (1.0f / 32.0f);
  float n2 = acc * acc;
#pragma unroll
  for (int mask = 1; mask < 16; mask <<= 1) n2 += __shfl_xor(n2, mask);
  float scale = sqrtf(n2) / (1.f + n2);
  v[(size_t)b * OF + t] = acc * scale;
}

// ---------------- Kernel C: wvT16[b,o,h] = bf16(sum_f W[h,o*16+f]*v[b,o,f])
// grid = 128 blocks: blk = hq*32 + o. W read exactly once device-wide.
__global__ __launch_bounds__(256) void k_wv(
    const float* __restrict__ W, const float* __restrict__ v,
    ushort* __restrict__ wvT16) {
  __shared__ float Ws[64 * 17];
  __shared__ float vsb[BB * 17];
  int t = threadIdx.x;
  int blk = blockIdx.x;
  int o = blk & 31, hq = blk >> 5;     // hq in [0,4)
#pragma unroll
  for (int jj = 0; jj < 4; ++jj) {
    int idx = jj * 256 + t;
    int hl = idx >> 4, f = idx & 15;
    Ws[hl * 17 + f] = W[((size_t)(hq * 64 + hl)) * OF + o * FF + f];
  }
#pragma unroll
  for (int jj = 0; jj < 8; ++jj) {
    int idx = jj * 256 + t;
    int b = idx >> 4, f = idx & 15;
    vsb[b * 17 + f] = v[((size_t)b * OO + o) * FF + f];
  }
  __syncthreads();
  int hl = t & 63, bq = t >> 6;
  for (int bb = 0; bb < BB; bb += 4) {
    int b = bb + bq;
    float acc = 0.f;
#pragma unroll
    for (int f = 0; f < FF; ++f) acc += Ws[hl * 17 + f] * vsb[b * 17 + f];
    wvT16[((size_t)b * OO + o) * HH + hq * 64 + hl] = f2bf(acc);
  }
}

// ---------------- Kernel D (fused): MFMA logits -> softmax -> VALU cx ------
// grid = B*NP (1024), block = 256 (4 waves), 3 blocks/CU (LDS ~51.7 KB)
__global__ __launch_bounds__(256, 3) void k_route(
    const float* __restrict__ x, const ushort* __restrict__ wvT16,
    ushort* __restrict__ cxp16) {
  __shared__ ushort x16[CI * X16STR];     // 33.8 KB  bf16 x tile [i][h]
  __shared__ float cs[OO * CSTRI];        // 8.7 KB   logits [o][i]
  __shared__ float c2[CI * C2STR];        // 9.2 KB   softmaxed c [i][o]
  int t = threadIdx.x;
  int blk = blockIdx.x;
  int b = blk >> 3, p = blk & 7;
  int lane = t & 63, wvid = t >> 6;
  int l16 = lane & 15, quad = lane >> 4;

  // ---- preload A-frags (Wv^T rows, [o][h] k-contiguous) from global ----
  int mt = wvid & 1;
  short8 afrag[8];
  {
    const ushort* wvp = wvT16 + ((size_t)b * OO + mt * 16 + l16) * HH + quad * 8;
#pragma unroll
    for (int ks = 0; ks < 8; ++ks)
      afrag[ks] = *(const short8*)(wvp + ks * 32);
  }

  // ---- stage x chunk [64][256] -> bf16 LDS ----
  {
    const float* xg = x + ((size_t)b * II + (size_t)p * CI) * HH;
#pragma unroll
    for (int j = 0; j < 16; ++j) {
      int idx = j * 256 + t;
      int row = idx >> 6, c4 = idx & 63;
      float4 v4 = *(const float4*)(xg + (size_t)row * HH + c4 * 4);
      ushort4 u;
      u.x = f2bf(v4.x); u.y = f2bf(v4.y); u.z = f2bf(v4.z); u.w = f2bf(v4.w);
      *(ushort4*)&x16[row * X16STR + c4 * 4] = u;
    }
  }
  __syncthreads();

  // ---- GEMM1 (MFMA): L^T[o][i], M=o (mt), N=i (nt), K=h (8 steps) ----
  {
    int nt0 = wvid >> 1;                 // this wave: nt0 and nt0+2
#pragma unroll
    for (int rep = 0; rep < 2; ++rep) {
      int nt = nt0 + rep * 2;
      floatx4 acc = {0.f, 0.f, 0.f, 0.f};
#pragma unroll
      for (int ks = 0; ks < 8; ++ks) {
        short8 bfrag = *(const short8*)&x16[(nt * 16 + l16) * X16STR + ks * 32 + quad * 8];
        acc = __builtin_amdgcn_mfma_f32_16x16x32_bf16(afrag[ks], bfrag, acc, 0, 0, 0);
      }
      // C layout: col=lane&15 -> i, row=quad*4+reg -> o  [m89-verified]
#pragma unroll
      for (int r = 0; r < 4; ++r)
        cs[(mt * 16 + quad * 4 + r) * CSTRI + nt * 16 + l16] = acc[r];
    }
  }
  __syncthreads();

  // ---- softmax over o (wave 0; lane = i, full column per lane) ----
  if (wvid == 0) {
    float lg[32];
    float m = -1e30f;
#pragma unroll
    for (int o = 0; o < 32; ++o) { lg[o] = cs[o * CSTRI + lane]; m = fmaxf(m, lg[o]); }
    float s = 0.f;
#pragma unroll
    for (int o = 0; o < 32; ++o) { lg[o] = __expf(lg[o] - m); s += lg[o]; }
    float inv = 1.f / s;
#pragma unroll
    for (int k = 0; k < 8; ++k) {
      float4 cc = make_float4(lg[4 * k] * inv, lg[4 * k + 1] * inv,
                              lg[4 * k + 2] * inv, lg[4 * k + 3] * inv);
      *(float4*)&c2[lane * C2STR + 4 * k] = cc;    // b128, conflict-free tiling
    }
  }
  __syncthreads();

  // ---- phase 3 (VALU): partial cx[o][h] = sum_i c2[i][o] * x16[i][h] ----
  {
    int hg = t & 63, og3 = t >> 6;       // og3 wave-uniform -> c2 reads broadcast
    int h0 = hg * 4, o0 = og3 * 8;
    float4 a4[8];
#pragma unroll
    for (int j = 0; j < 8; ++j) a4[j] = make_float4(0.f, 0.f, 0.f, 0.f);
#pragma unroll 4
    for (int i = 0; i < CI; ++i) {
      ushort4 xu = *(const ushort4*)&x16[i * X16STR + h0];
      float4 x4 = make_float4(bf2f(xu.x), bf2f(xu.y), bf2f(xu.z), bf2f(xu.w));
      float4 c0 = *(const float4*)&c2[i * C2STR + o0];
      float4 c1 = *(const float4*)&c2[i * C2STR + o0 + 4];
      float cv[8] = {c0.x, c0.y, c0.z, c0.w, c1.x, c1.y, c1.z, c1.w};
#pragma unroll
      for (int j = 0; j < 8; ++j) {
        a4[j].x += cv[j] * x4.x;
        a4[j].y += cv[j] * x4.y;
        a4[j].z += cv[j] * x4.z;
        a4[j].w += cv[j] * x4.w;
      }
    }
    ushort* outp = cxp16 + ((size_t)blk * OO + o0) * HH + h0;
#pragma unroll
    for (int j = 0; j < 8; ++j) {
      ushort4 u;
      u.x = f2bf(a4[j].x); u.y = f2bf(a4[j].y);
      u.z = f2bf(a4[j].z); u.w = f2bf(a4[j].w);
      *(ushort4*)&outp[(size_t)j * HH] = u;        // coalesced 8B/lane
    }
  }
}

// ---------------- Kernel E: reduce partials + v = squash(cx @ W) -----------
// grid = B*O (4096), block = 256
__global__ __launch_bounds__(256) void k_v2(
    const ushort* __restrict__ cxp16, const float* __restrict__ W,
    float* __restrict__ v, float* __restrict__ out, int final_) {
  __shared__ float cxs[HH];
  __shared__ float red[4][16];
  int t = threadIdx.x;
  int blk = blockIdx.x;                // b*32 + o
  int b = blk >> 5, o = blk & 31;
  {
    const ushort* cp = cxp16 + (((size_t)b * NP) * OO + o) * HH + t;
    float a = 0.f;
#pragma unroll
    for (int p = 0; p < NP; ++p) a += bf2f(cp[(size_t)p * OO * HH]);
    cxs[t] = a;
  }
  __syncthreads();
  int f = t & 15, hq = t >> 4;
  const float* wp = W + (size_t)hq * 16 * OF + o * FF + f;
  float acc = 0.f;
#pragma unroll
  for (int j = 0; j < 16; ++j)
    acc += cxs[hq * 16 + j] * wp[(size_t)j * OF];
  acc += __shfl_xor(acc, 16);
  acc += __shfl_xor(acc, 32);
  if ((t & 63) < 16) red[t >> 6][f] = acc;
  __syncthreads();
  if (t < 16) {
    float a = red[0][t] + red[1][t] + red[2][t] + red[3][t];
    float n2 = a * a;
#pragma unroll
    for (int mask = 1; mask < 16; mask <<= 1) n2 += __shfl_xor(n2, mask);
    float scale = sqrtf(n2) / (1.f + n2);
    float res = a * scale;
    if (final_) out[(size_t)blk * FF + t] = res;
    else v[(size_t)blk * FF + t] = res;
  }
}

extern "C" void kernel_launch(void* const* d_in, const int* in_sizes, int n_in,
                              void* d_out, int out_size, void* d_ws, size_t ws_size,
                              hipStream_t stream) {
  const float* x = (const float*)d_in[0];  // [128,512,256] fp32
  const float* W = (const float*)d_in[1];  // [1,256,512]   fp32
  float* out = (float*)d_out;              // [128,32,16]   fp32
  float* ws = (float*)d_ws;
  // workspace (floats): total 5,046,272 = 20.2 MiB
  float*  xsum_part = ws;                        // 262144
  float*  v     = ws + 262144;                   // 65536
  ushort* wvT16 = (ushort*)(ws + 327680);        // B*O*H bf16 (524288 floats)
  ushort* cxp16 = (ushort*)(ws + 851968);        // B*NP*O*H bf16 (4194304 floats)

  k_xsum<<<BB * 8, 256, 0, stream>>>(x, xsum_part);
  k_v1<<<BB, 512, 0, stream>>>(xsum_part, W, v);
  for (int it = 0; it < 2; ++it) {
    k_wv<<<128, 256, 0, stream>>>(W, v, wvT16);
    k_route<<<BB * NP, 256, 0, stream>>>(x, wvT16, cxp16);
    k_v2<<<BB * OO, 256, 0, stream>>>(cxp16, W, v, out, it == 1);
  }
}